// Round 2
// baseline (377.768 us; speedup 1.0000x reference)
//
#include <hip/hip_runtime.h>
#include <cmath>

#define B_ROWS 16384
#define E_DIM 512
#define H_DIM 1024
#define P_DIM 256
#define K1_RAW 1026
#define K1_PAD 1152   // multiple of 128 -> even number of 64-K tiles

#define NEG_BIG (-3.0e38f)
#define SCL_IN  16.0f            // fp8 pre-scale for A1 and all weights
#define INV_G1  (1.0f / 256.0f)  // GEMM1: A(x16) * W(x16)
#define INV_G   (1.0f / 16.0f)   // GEMM2-4: A(x1) * W(x16)

typedef __attribute__((ext_vector_type(4))) short short4v;
typedef __attribute__((ext_vector_type(8))) short short8v;
typedef __attribute__((ext_vector_type(4))) float f32x4;
typedef __attribute__((ext_vector_type(2))) long long2v;

__device__ __forceinline__ short f2bf(float f) {
    unsigned u = __float_as_uint(f);
    u += 0x7fffu + ((u >> 16) & 1u);   // round-to-nearest-even
    return (short)(u >> 16);
}
__device__ __forceinline__ float bf2f(short s) {
    return __uint_as_float(((unsigned)(unsigned short)s) << 16);
}
// pack 4 floats -> 4 OCP e4m3 bytes (HW cvt, RNE+sat)
__device__ __forceinline__ int pk4_fp8(float a, float b, float c, float d) {
    int v = __builtin_amdgcn_cvt_pk_fp8_f32(a, b, 0, false);
    return  __builtin_amdgcn_cvt_pk_fp8_f32(c, d, v, true);
}

// K-interleave permutation: within each 64-k block, store the 8 eight-byte
// MFMA quad-chunks as [A0 B0 A1 B1 A2 B2 A3 B3] so one b128 read at quad*16
// returns {k-step0 frag, k-step1 frag} for mfma_16x16x32_fp8_fp8.
__device__ __forceinline__ int kperm(int k) {
    return (k & ~63) | (((k >> 3) & 3) << 4) | (((k >> 5) & 1) << 3) | (k & 7);
}

// async global->LDS DMA, 16 B/lane; lds dest = wave-uniform base + lane*16
__device__ __forceinline__ void g2lds16(const void* g, void* l) {
    __builtin_amdgcn_global_load_lds(
        (const __attribute__((address_space(1))) void*)g,
        (__attribute__((address_space(3))) void*)l, 16, 0, 0);
}

// ---------------------------------------------------------------------------
// prep_all: one launch covering (a) per-row L2 norm + fp8 A1 emit (blocks
// 0..16383) and (b) all four weight transpose+cvt jobs (trailing 864 blocks).
#define NTB_Z0 288   // K1_PAD/64 * H/64 = 18*16
#define NTB_Z1 256
#define NTB_Z2 256
#define NTB_Z3 64    // 16 * P/64
#define NTB_ALL (NTB_Z0 + NTB_Z1 + NTB_Z2 + NTB_Z3)

__global__ __launch_bounds__(256) void prep_all(
    const float* __restrict__ x1, const float* __restrict__ x2,
    const float* __restrict__ gf, char* __restrict__ A1,
    const float* __restrict__ W0, char* __restrict__ Wt0,
    const float* __restrict__ W1, char* __restrict__ Wt1,
    const float* __restrict__ W2, char* __restrict__ Wt2,
    const float* __restrict__ W3, char* __restrict__ Wt3)
{
    __shared__ float T[64][68];
    const int t = threadIdx.x;
    const int bid = blockIdx.x;

    if (bid < B_ROWS) {
        // ---- prep_a1 body ----
        const int b = bid;
        float* red = &T[0][0];

        const float* src = (t < 128) ? x1 : x2;
        const int idx = (t & 127) << 2;
        float4 v = *(const float4*)&src[(size_t)b * E_DIM + idx];
        float ss = v.x*v.x + v.y*v.y + v.z*v.z + v.w*v.w;
        #pragma unroll
        for (int off = 32; off > 0; off >>= 1) ss += __shfl_xor(ss, off, 64);
        if ((t & 63) == 0) red[t >> 6] = ss;
        __syncthreads();
        const float inv1 = SCL_IN / fmaxf(sqrtf(red[0] + red[1]), 1e-12f);
        const float inv2 = SCL_IN / fmaxf(sqrtf(red[2] + red[3]), 1e-12f);
        const float iv = (t < 128) ? inv1 : inv2;

        const size_t rb = (size_t)b * K1_PAD;
        *(int*)&A1[rb + kperm(t << 2)] = pk4_fp8(v.x * iv, v.y * iv, v.z * iv, v.w * iv);
        if (t < 32) {
            const int k = 1024 + (t << 2);
            float vals[4];
            #pragma unroll
            for (int i = 0; i < 4; ++i) {
                int kk = k + i;
                vals[i] = (kk == 1024) ? gf[(size_t)b * 2 + 0] * SCL_IN
                        : (kk == 1025) ? gf[(size_t)b * 2 + 1] * SCL_IN : 0.f;
            }
            *(int*)&A1[rb + kperm(k)] = pk4_fp8(vals[0], vals[1], vals[2], vals[3]);
        }
        return;
    }

    // ---- transpose body ----
    int tb = bid - B_ROWS;
    const float* W; char* Wt; int K, N, Kpad, kx, ny;
    if (tb < NTB_Z0)                   { W = W0; Wt = Wt0; K = K1_RAW; N = H_DIM; Kpad = K1_PAD; kx = tb % 18; ny = tb / 18; }
    else if (tb < NTB_Z0 + NTB_Z1)     { tb -= NTB_Z0;          W = W1; Wt = Wt1; K = H_DIM; N = H_DIM; Kpad = H_DIM; kx = tb & 15; ny = tb >> 4; }
    else if (tb < NTB_Z0 + NTB_Z1 + NTB_Z2) { tb -= NTB_Z0 + NTB_Z1; W = W2; Wt = Wt2; K = H_DIM; N = H_DIM; Kpad = H_DIM; kx = tb & 15; ny = tb >> 4; }
    else                               { tb -= NTB_Z0 + NTB_Z1 + NTB_Z2; W = W3; Wt = Wt3; K = H_DIM; N = P_DIM; Kpad = H_DIM; kx = tb & 15; ny = tb >> 4; }

    const int k0 = kx * 64, n0 = ny * 64;
    const int r = t >> 4;          // 0..15
    const int c = (t & 15) << 2;   // 0..60
    #pragma unroll
    for (int rr = 0; rr < 4; ++rr) {
        int k = k0 + r + rr * 16;
        float4 v = (k < K) ? *(const float4*)&W[(size_t)k * N + n0 + c]
                           : make_float4(0.f, 0.f, 0.f, 0.f);
        v.x *= SCL_IN; v.y *= SCL_IN; v.z *= SCL_IN; v.w *= SCL_IN;
        *(float4*)&T[r + rr * 16][c] = v;
    }
    __syncthreads();
    const int n = n0 + (t >> 2);
    const int cn = t >> 2;
    const int ks = (t & 3) << 4;   // 0,16,32,48
    #pragma unroll
    for (int g = 0; g < 2; ++g) {
        int kk = ks + g * 8;
        int lo = pk4_fp8(T[kk+0][cn], T[kk+1][cn], T[kk+2][cn], T[kk+3][cn]);
        int hi = pk4_fp8(T[kk+4][cn], T[kk+5][cn], T[kk+6][cn], T[kk+7][cn]);
        int2 o = { lo, hi };
        int np = k0 + (((kk >> 3) & 3) << 4) + (((kk >> 5) & 1) << 3);
        *(int2*)&Wt[(size_t)n * Kpad + np] = o;
    }
}

// ---------------------------------------------------------------------------
// gemm_ln: fused row-panel GEMM + LN(+ReLU)(+residual) epilogue.
// Block = 64 rows x full N (NF*16 cols per wave x 8 waves). Grid = B/64 = 256
// blocks = exactly 1/CU. 512 thr = 8 waves, all sharing the same 64 A-rows
// (wave-tile 64 x NF*16).
// K-loop: A staged in LDS (4KB/tile, tile-PAIRS double-buffered, ONE barrier
// per 2 k-tiles = 128 MFMA/wave between barriers); B-fragments read per-lane
// straight from global (Wt is <=1.1MB, L2-resident; kperm layout makes each
// 16-lane group read full 64B lines).
// EPI==0: per-row LN stats (shfl + LDS cross-wave reduce) -> chunked LDS
//   re-layout -> LN+ReLU (+res) -> fp8(kperm) act + optional bf16 residual.
// EPI==1: final LN (N=256) + classifier (P->7) + gender mask -> out.
template <int KA, int NF, int EPI, int HAS_RES, int WRITE_BF>
__global__ __launch_bounds__(512, 2) void gemm_ln(
    const char* A, const char* __restrict__ Bt,
    const float* __restrict__ bias, float cscale,
    const float* __restrict__ gamma, const float* __restrict__ beta,
    const short* __restrict__ res,
    char* actout, short* __restrict__ fbout,
    const float* __restrict__ Wc, const float* __restrict__ bc,
    const float* __restrict__ gfeat, float* __restrict__ outp)
{
    constexpr int NT = KA >> 6;       // 64-K tiles
    constexpr int NI = NT >> 1;       // iterations (pair of tiles each)
    static_assert((NT & 1) == 0 && NT >= 4, "need even tile count");
    constexpr int NCOL = NF * 16 * 8; // total N of this layer

    __shared__ __align__(16) char sA[2][8192];   // [buf][tile pair: 2x 64x64]
    __shared__ float red[8][64][2];              // per-wave row partials
    __shared__ float mr[64][2];                  // mean / rstd per row
    __shared__ short xs[64][264];                // bf16 re-layout buffer

    const int t = threadIdx.x;
    const int w = t >> 6, lane = t & 63;
    const int wu = __builtin_amdgcn_readfirstlane(w);
    const int m16 = lane & 15, quad = lane >> 4;
    const int row0 = blockIdx.x * 64;
    const int colw = w * (NF * 16);

    // per-thread global source for A staging (thread t stages 16B of the pair)
    const char* Ast = A + (size_t)(row0 + ((t >> 2) & 63)) * KA
                        + ((t >> 8) * 64) + ((t & 3) * 16);

    // per-lane B fragment base pointers (frag j, this wave's columns)
    const char* Bp[NF];
    #pragma unroll
    for (int j = 0; j < NF; ++j)
        Bp[j] = Bt + (size_t)(colw + j * 16 + m16) * KA + quad * 16;

    f32x4 acc[4][NF];
    #pragma unroll
    for (int i = 0; i < 4; ++i)
        #pragma unroll
        for (int j = 0; j < NF; ++j)
            acc[i][j] = (f32x4){0.f, 0.f, 0.f, 0.f};

    auto stage = [&](int pair) {
        g2lds16(Ast + (size_t)pair * 128, (char*)sA + (pair & 1) * 8192 + (wu << 10));
    };

    stage(0);

    #pragma unroll 1
    for (int it = 0; it < NI; ++it) {
        // all LDS reads of prev iter drained + this iter's A pair resident
        asm volatile("s_waitcnt vmcnt(0) lgkmcnt(0)\n\ts_barrier" ::: "memory");
        if (it + 1 < NI) stage(it + 1);

        const char* Abuf = (const char*)sA + (it & 1) * 8192;
        #pragma unroll
        for (int tt = 0; tt < 2; ++tt) {
            const int T = 2 * it + tt;
            long2v af[4], bf[NF];
            #pragma unroll
            for (int i = 0; i < 4; ++i)
                af[i] = *(const long2v*)&Abuf[tt * 4096 + (i * 16 + m16) * 64 + quad * 16];
            #pragma unroll
            for (int j = 0; j < NF; ++j)
                bf[j] = *(const long2v*)(Bp[j] + (size_t)T * 64);
            #pragma unroll
            for (int i = 0; i < 4; ++i)
                #pragma unroll
                for (int j = 0; j < NF; ++j) {
                    acc[i][j] = __builtin_amdgcn_mfma_f32_16x16x32_fp8_fp8(
                        af[i][0], bf[j][0], acc[i][j], 0, 0, 0);
                    acc[i][j] = __builtin_amdgcn_mfma_f32_16x16x32_fp8_fp8(
                        af[i][1], bf[j][1], acc[i][j], 0, 0, 0);
                }
        }
    }

    // ---- per-row LN statistics (rows 0..63 shared by all 8 waves) ----
    float bj[NF];
    #pragma unroll
    for (int j = 0; j < NF; ++j) bj[j] = bias[colw + j * 16 + m16];

    #pragma unroll
    for (int i = 0; i < 4; ++i)
        #pragma unroll
        for (int r = 0; r < 4; ++r) {
            float s = 0.f, ss = 0.f;
            #pragma unroll
            for (int j = 0; j < NF; ++j) {
                float x = acc[i][j][r] * cscale + bj[j];
                s += x; ss += x * x;
            }
            #pragma unroll
            for (int off = 1; off <= 8; off <<= 1) {
                s  += __shfl_xor(s,  off, 64);
                ss += __shfl_xor(ss, off, 64);
            }
            if (m16 == 0) {
                const int ri = i * 16 + quad * 4 + r;
                red[w][ri][0] = s; red[w][ri][1] = ss;
            }
        }
    __syncthreads();
    if (t < 64) {
        float s = 0.f, ss = 0.f;
        #pragma unroll
        for (int ww = 0; ww < 8; ++ww) { s += red[ww][t][0]; ss += red[ww][t][1]; }
        const float mm = s * (1.f / NCOL);
        mr[t][0] = mm;
        mr[t][1] = 1.f / sqrtf(fmaxf(ss * (1.f / NCOL) - mm * mm, 0.f) + 1e-5f);
    }
    __syncthreads();

    if constexpr (EPI == 0) {
        // ---- chunked re-layout + LN + ReLU (+res) -> fp8 act / bf16 fb ----
        const int prow = t >> 3;      // 0..63
        const int pcg  = t & 7;
        #pragma unroll
        for (int ch = 0; ch < NCOL / 256; ++ch) {
            __syncthreads();
            if ((w >> 1) == ch) {
                const int cw = (w & 1) * 128;
                #pragma unroll
                for (int i = 0; i < 4; ++i)
                    #pragma unroll
                    for (int j = 0; j < NF; ++j)
                        #pragma unroll
                        for (int r = 0; r < 4; ++r)
                            xs[i * 16 + quad * 4 + r][cw + j * 16 + m16] =
                                f2bf(acc[i][j][r] * cscale + bj[j]);
            }
            __syncthreads();
            const float mm = mr[prow][0], rs = mr[prow][1];
            const size_t gr = (size_t)(row0 + prow);
            #pragma unroll
            for (int g = 0; g < 4; ++g) {
                const int c  = pcg * 8 + g * 64;
                const int gc = ch * 256 + c;
                short8v xv = *(const short8v*)&xs[prow][c];
                float4 g0 = *(const float4*)&gamma[gc];
                float4 g1 = *(const float4*)&gamma[gc + 4];
                float4 b0 = *(const float4*)&beta[gc];
                float4 b1 = *(const float4*)&beta[gc + 4];
                const float gv[8] = {g0.x,g0.y,g0.z,g0.w,g1.x,g1.y,g1.z,g1.w};
                const float bv[8] = {b0.x,b0.y,b0.z,b0.w,b1.x,b1.y,b1.z,b1.w};
                float y[8];
                #pragma unroll
                for (int e = 0; e < 8; ++e)
                    y[e] = fmaxf((bf2f(xv[e]) - mm) * rs * gv[e] + bv[e], 0.f);
                if constexpr (HAS_RES) {
                    short8v rr = *(const short8v*)&res[gr * H_DIM + gc];
                    #pragma unroll
                    for (int e = 0; e < 8; ++e) y[e] += bf2f(rr[e]);
                }
                int2 o = { pk4_fp8(y[0], y[1], y[2], y[3]),
                           pk4_fp8(y[4], y[5], y[6], y[7]) };
                *(int2*)&actout[gr * H_DIM + kperm(gc)] = o;
                if constexpr (WRITE_BF) {
                    short8v ov = { f2bf(y[0]), f2bf(y[1]), f2bf(y[2]), f2bf(y[3]),
                                   f2bf(y[4]), f2bf(y[5]), f2bf(y[6]), f2bf(y[7]) };
                    *(short8v*)&fbout[gr * H_DIM + gc] = ov;
                }
            }
        }
    } else {
        // ---- final LN + classifier + gender mask ----
        #pragma unroll
        for (int i = 0; i < 4; ++i)
            #pragma unroll
            for (int j = 0; j < NF; ++j)
                #pragma unroll
                for (int r = 0; r < 4; ++r)
                    xs[i * 16 + quad * 4 + r][colw + j * 16 + m16] =
                        f2bf(acc[i][j][r] * cscale + bj[j]);
        __syncthreads();
        #pragma unroll
        for (int rr = 0; rr < 8; ++rr) {
            const int row = w * 8 + rr;
            const float mm = mr[row][0], rs = mr[row][1];
            const int c = lane * 4;
            short4v xv = *(const short4v*)&xs[row][c];
            float4 ga = *(const float4*)&gamma[c];
            float4 ba = *(const float4*)&beta[c];
            const float gv[4] = {ga.x, ga.y, ga.z, ga.w};
            const float bvv[4] = {ba.x, ba.y, ba.z, ba.w};
            float p[7] = {0.f, 0.f, 0.f, 0.f, 0.f, 0.f, 0.f};
            #pragma unroll
            for (int e = 0; e < 4; ++e) {
                const float yv = fmaxf((bf2f(xv[e]) - mm) * rs * gv[e] + bvv[e], 0.f);
                const float* wr = &Wc[(c + e) * 7];
                #pragma unroll
                for (int c7 = 0; c7 < 7; ++c7) p[c7] += yv * wr[c7];
            }
            #pragma unroll
            for (int off = 32; off > 0; off >>= 1)
                #pragma unroll
                for (int c7 = 0; c7 < 7; ++c7) p[c7] += __shfl_xor(p[c7], off, 64);
            if (lane == 0) {
                const size_t gr = (size_t)(row0 + row);
                int g1 = (gfeat[gr * 2 + 0] != 0.f);
                int g2 = (gfeat[gr * 2 + 1] != 0.f);
                unsigned bits = (g1 == g2) ? (g1 ? 0x24u : 0x12u) : 0x49u;
                #pragma unroll
                for (int c7 = 0; c7 < 7; ++c7)
                    outp[gr * 7 + c7] = ((bits >> c7) & 1u) ? p[c7] + bc[c7] : NEG_BIG;
            }
        }
    }
}

// ---------------------------------------------------------------------------
extern "C" void kernel_launch(void* const* d_in, const int* in_sizes, int n_in,
                              void* d_out, int out_size, void* d_ws, size_t ws_size,
                              hipStream_t stream)
{
    const float* x1   = (const float*)d_in[0];
    const float* x2   = (const float*)d_in[1];
    const float* gf   = (const float*)d_in[2];
    const float* W_in = (const float*)d_in[3];
    const float* b_in = (const float*)d_in[4];
    const float* g_in = (const float*)d_in[5];
    const float* be_in = (const float*)d_in[6];
    const float* W_r1 = (const float*)d_in[7];
    const float* b_r1 = (const float*)d_in[8];
    const float* g_r1 = (const float*)d_in[9];
    const float* be_r1 = (const float*)d_in[10];
    const float* W_r2 = (const float*)d_in[11];
    const float* b_r2 = (const float*)d_in[12];
    const float* g_r2 = (const float*)d_in[13];
    const float* be_r2 = (const float*)d_in[14];
    const float* W_f  = (const float*)d_in[15];
    const float* b_f  = (const float*)d_in[16];
    const float* g_f  = (const float*)d_in[17];
    const float* be_f = (const float*)d_in[18];
    const float* W_c  = (const float*)d_in[19];
    const float* b_c  = (const float*)d_in[20];
    float* out = (float*)d_out;

    const int B = B_ROWS;

    // ---- workspace layout ----
    char* p = (char*)d_ws;
    char*  A1    = p;            p += (size_t)B * K1_PAD;            // fp8, stride 1152
    char*  act   = p;            p += (size_t)B * H_DIM;             // fp8, stride 1024 (in-place reused)
    short* fb    = (short*)p;    p += (size_t)B * H_DIM * 2;         // bf16 running residual
    char*  Wt_in = p;            p += (size_t)H_DIM * K1_PAD;
    char*  Wt_r1 = p;            p += (size_t)H_DIM * H_DIM;
    char*  Wt_r2 = p;            p += (size_t)H_DIM * H_DIM;
    char*  Wt_f  = p;            p += (size_t)P_DIM * H_DIM;

    // 1) prep (L2 norm + fp8 A1) + all weight transposes, one launch
    prep_all<<<B + NTB_ALL, 256, 0, stream>>>(
        x1, x2, gf, A1,
        W_in, Wt_in, W_r1, Wt_r1, W_r2, Wt_r2, W_f, Wt_f);

    // 2) input_proj GEMM + LN + ReLU -> act fp8 + fb bf16
    gemm_ln<K1_PAD, 8, 0, 0, 1><<<B / 64, 512, 0, stream>>>(
        A1, Wt_in, b_in, INV_G1, g_in, be_in, nullptr, act, fb,
        nullptr, nullptr, nullptr, nullptr);

    // 3) residual block 1 (act in-place, fb in-place)
    gemm_ln<H_DIM, 8, 0, 1, 1><<<B / 64, 512, 0, stream>>>(
        act, Wt_r1, b_r1, INV_G, g_r1, be_r1, fb, act, fb,
        nullptr, nullptr, nullptr, nullptr);

    // 4) residual block 2 (no residual-out needed)
    gemm_ln<H_DIM, 8, 0, 1, 0><<<B / 64, 512, 0, stream>>>(
        act, Wt_r2, b_r2, INV_G, g_r2, be_r2, fb, act, nullptr,
        nullptr, nullptr, nullptr, nullptr);

    // 5) final_proj + final LN + classifier + gender mask
    gemm_ln<H_DIM, 2, 1, 0, 0><<<B / 64, 512, 0, stream>>>(
        act, Wt_f, b_f, INV_G, g_f, be_f, nullptr, nullptr, nullptr,
        W_c, b_c, gf, out);
}